// Round 7
// baseline (428.156 us; speedup 1.0000x reference)
//
#include <hip/hip_runtime.h>
#include <math.h>

// Problem constants (from reference setup_inputs)
#define T_TOKENS 16384
#define DIM      2048
#define NEXP     64
#define TOPK     2

#define NSUB  4              // k-subranges per block (one per wave)
#define KC    (DIM / NSUB)   // 512 k's per wave
#define PS    20             // partial-tile stride (floats): 80 B, 16B-aligned
#define FS    68             // finish-kernel logit row stride

// Flat fp32 output layout: combine | topk_idx | gates | expert_activation
#define OFF_COMBINE 0
#define OFF_IDX     (T_TOKENS * NEXP)
#define OFF_GATES   (OFF_IDX + T_TOKENS * TOPK)
#define OFF_ACT     (OFF_GATES + T_TOKENS * TOPK)

__device__ __forceinline__ void fma16v(float* acc, float xs,
                                       const float4 w0, const float4 w1,
                                       const float4 w2, const float4 w3) {
    acc[0]  = fmaf(xs, w0.x, acc[0]);  acc[1]  = fmaf(xs, w0.y, acc[1]);
    acc[2]  = fmaf(xs, w0.z, acc[2]);  acc[3]  = fmaf(xs, w0.w, acc[3]);
    acc[4]  = fmaf(xs, w1.x, acc[4]);  acc[5]  = fmaf(xs, w1.y, acc[5]);
    acc[6]  = fmaf(xs, w1.z, acc[6]);  acc[7]  = fmaf(xs, w1.w, acc[7]);
    acc[8]  = fmaf(xs, w2.x, acc[8]);  acc[9]  = fmaf(xs, w2.y, acc[9]);
    acc[10] = fmaf(xs, w2.z, acc[10]); acc[11] = fmaf(xs, w2.w, acc[11]);
    acc[12] = fmaf(xs, w3.x, acc[12]); acc[13] = fmaf(xs, w3.y, acc[13]);
    acc[14] = fmaf(xs, w3.z, acc[14]); acc[15] = fmaf(xs, w3.w, acc[15]);
}

// K1: GEMM with a memory-clean K-loop:
//   - w: uniform-address global_load_dwordx4 (vmcnt path; ds_bpermute taint
//     keeps the address in a VGPR so LLVM can't promote to the serial s_load
//     path — R6 evidence: that alone took VALUBusy 28% -> 64%).
//   - x: per-lane divergent global stream (lane = row), register-pipelined
//     2 bodies ahead (R3's proven loop). No LDS, no barriers in the K-loop.
// Grid 1024 = 256 row-tiles x 4 expert-groups -> exactly 4 blocks/CU, one
// generation. Block = 256 thr = 4 waves = 4 k-subranges; acc16/lane.
// __launch_bounds__(256,4): 128-VGPR cap fits acc16 + 16 w-float4 + x pipe.
__global__ __launch_bounds__(256, 4)
void gemm_kernel(const float* __restrict__ x,
                 const float* __restrict__ w,     // [DIM][NEXP]
                 float* __restrict__ out) {       // logits -> combine region
    __shared__ float part[NSUB][64][PS];          // 20 KB partial reduce only

    const int tid  = threadIdx.x;
    const int lane = tid & 63;
    const int wv   = __builtin_amdgcn_readfirstlane(tid >> 6);  // k-subrange
    const int tile = blockIdx.x >> 2;
    const int eg   = blockIdx.x & 3;              // experts [eg*16, eg*16+16)
    const int row  = tile * 64 + lane;
    const int k0   = wv * KC;
    const int e0   = eg * 16;

    if (blockIdx.x == 0 && tid < NEXP) out[OFF_ACT + tid] = 0.0f;

    // Opaque zero: keeps w addresses in VGPRs so loads stay on VMEM.
    const int vz = __builtin_amdgcn_ds_bpermute(0, 0);

    float acc[16];
    #pragma unroll
    for (int i = 0; i < 16; ++i) acc[i] = 0.0f;

    const float* __restrict__ xp = x + (size_t)row * DIM + k0;
    const float* __restrict__ wp = w + vz + (size_t)k0 * NEXP + e0;

    float4 X = *reinterpret_cast<const float4*>(xp);
    float4 Y = *reinterpret_cast<const float4*>(xp + 4);

    #pragma unroll 1
    for (int kk = 0; kk < KC; kk += 4) {
        const float* __restrict__ wr = wp + (size_t)kk * NEXP;
        // 16 uniform dwordx4 loads: 4 k-rows x 16 experts, all issued up front.
        const float4 a0 = *reinterpret_cast<const float4*>(wr + 0);
        const float4 a1 = *reinterpret_cast<const float4*>(wr + 4);
        const float4 a2 = *reinterpret_cast<const float4*>(wr + 8);
        const float4 a3 = *reinterpret_cast<const float4*>(wr + 12);
        const float4 b0 = *reinterpret_cast<const float4*>(wr + NEXP + 0);
        const float4 b1 = *reinterpret_cast<const float4*>(wr + NEXP + 4);
        const float4 b2 = *reinterpret_cast<const float4*>(wr + NEXP + 8);
        const float4 b3 = *reinterpret_cast<const float4*>(wr + NEXP + 12);
        const float4 c0 = *reinterpret_cast<const float4*>(wr + 2 * NEXP + 0);
        const float4 c1 = *reinterpret_cast<const float4*>(wr + 2 * NEXP + 4);
        const float4 c2 = *reinterpret_cast<const float4*>(wr + 2 * NEXP + 8);
        const float4 c3 = *reinterpret_cast<const float4*>(wr + 2 * NEXP + 12);
        const float4 d0 = *reinterpret_cast<const float4*>(wr + 3 * NEXP + 0);
        const float4 d1 = *reinterpret_cast<const float4*>(wr + 3 * NEXP + 4);
        const float4 d2 = *reinterpret_cast<const float4*>(wr + 3 * NEXP + 8);
        const float4 d3 = *reinterpret_cast<const float4*>(wr + 3 * NEXP + 12);
        // x prefetch 2 bodies ahead (clamped: harmless L1-hit on last 2 iters).
        const int kpre = (kk + 8 < KC) ? (kk + 8) : 0;
        const float4 Z = *reinterpret_cast<const float4*>(xp + kpre);

        fma16v(acc, X.x, a0, a1, a2, a3);
        fma16v(acc, X.y, b0, b1, b2, b3);
        fma16v(acc, X.z, c0, c1, c2, c3);
        fma16v(acc, X.w, d0, d1, d2, d3);

        X = Y; Y = Z;
    }

    // Reduce the 4 k-subrange partials in LDS; one coalesced float4 store.
    {
        float* pr = &part[wv][lane][0];
        *reinterpret_cast<float4*>(pr + 0)  = make_float4(acc[0],  acc[1],  acc[2],  acc[3]);
        *reinterpret_cast<float4*>(pr + 4)  = make_float4(acc[4],  acc[5],  acc[6],  acc[7]);
        *reinterpret_cast<float4*>(pr + 8)  = make_float4(acc[8],  acc[9],  acc[10], acc[11]);
        *reinterpret_cast<float4*>(pr + 12) = make_float4(acc[12], acc[13], acc[14], acc[15]);
    }
    __syncthreads();
    {
        const int r = tid >> 2, c = (tid & 3) * 4;
        float4 s        = *reinterpret_cast<const float4*>(&part[0][r][c]);
        const float4 s1 = *reinterpret_cast<const float4*>(&part[1][r][c]);
        const float4 s2 = *reinterpret_cast<const float4*>(&part[2][r][c]);
        const float4 s3 = *reinterpret_cast<const float4*>(&part[3][r][c]);
        s.x += s1.x + s2.x + s3.x;
        s.y += s1.y + s2.y + s3.y;
        s.z += s1.z + s2.z + s3.z;
        s.w += s1.w + s2.w + s3.w;
        *reinterpret_cast<float4*>(
            out + OFF_COMBINE + (size_t)(tile * 64 + r) * NEXP + e0 + c) = s;
    }
}

// K2: logits (in combine region) + noise; top-2 + renormalized gates; writes
// all outputs, overwriting the logits with the combine tensor.
__global__ __launch_bounds__(1024)
void finish_kernel(const float* __restrict__ noise,
                   float* __restrict__ out) {
    __shared__ float lg[64][FS];
    __shared__ float g1s[64], g2s[64];
    __shared__ int   i1s[64], i2s[64];
    __shared__ float bins[NEXP];

    const int tid = threadIdx.x;
    const int r = tid >> 4, c = (tid & 15) * 4;
    const size_t rowbase = (size_t)(blockIdx.x * 64 + r) * NEXP + c;

    float4 a       = *reinterpret_cast<const float4*>(out + OFF_COMBINE + rowbase);
    const float4 n = *reinterpret_cast<const float4*>(noise + rowbase);
    a.x += n.x; a.y += n.y; a.z += n.z; a.w += n.w;
    *reinterpret_cast<float4*>(&lg[r][c]) = a;
    if (tid < NEXP) bins[tid] = 0.0f;
    __syncthreads();

    if (tid < 64) {   // wave 0, lane = row
        const int rr = tid;
        float m1 = -1e30f, m2 = -1e30f;
        int i1 = 0, i2 = 0;
        #pragma unroll
        for (int j = 0; j < NEXP; j += 4) {
            const float4 s = *reinterpret_cast<const float4*>(&lg[rr][j]);
            if (s.x > m1) { m2 = m1; i2 = i1; m1 = s.x; i1 = j + 0; } else if (s.x > m2) { m2 = s.x; i2 = j + 0; }
            if (s.y > m1) { m2 = m1; i2 = i1; m1 = s.y; i1 = j + 1; } else if (s.y > m2) { m2 = s.y; i2 = j + 1; }
            if (s.z > m1) { m2 = m1; i2 = i1; m1 = s.z; i1 = j + 2; } else if (s.z > m2) { m2 = s.z; i2 = j + 2; }
            if (s.w > m1) { m2 = m1; i2 = i1; m1 = s.w; i1 = j + 3; } else if (s.w > m2) { m2 = s.w; i2 = j + 3; }
        }
        // Softmax Z cancels under top-2 renorm: g1 = 1/(1+exp(l2-l1)).
        const float t  = expf(m2 - m1);
        const float g1 = 1.0f / (1.0f + t);
        const float g2 = 1.0f - g1;

        const int row = blockIdx.x * 64 + rr;
        out[OFF_IDX + row * 2 + 0]   = (float)i1;
        out[OFF_IDX + row * 2 + 1]   = (float)i2;
        out[OFF_GATES + row * 2 + 0] = g1;
        out[OFF_GATES + row * 2 + 1] = g2;

        g1s[rr] = g1; g2s[rr] = g2; i1s[rr] = i1; i2s[rr] = i2;
        atomicAdd(&bins[i1], 1.0f);
        atomicAdd(&bins[i2], 1.0f);
    }
    __syncthreads();

    {
        const int   ia = i1s[r], ib = i2s[r];
        const float ga = g1s[r], gb = g2s[r];
        float4 v;
        v.x = (c + 0 == ia) ? ga : (c + 0 == ib) ? gb : 0.0f;
        v.y = (c + 1 == ia) ? ga : (c + 1 == ib) ? gb : 0.0f;
        v.z = (c + 2 == ia) ? ga : (c + 2 == ib) ? gb : 0.0f;
        v.w = (c + 3 == ia) ? ga : (c + 3 == ib) ? gb : 0.0f;
        *reinterpret_cast<float4*>(out + OFF_COMBINE + rowbase) = v;
    }

    if (tid < NEXP) {
        const float v = bins[tid];
        if (v != 0.0f) atomicAdd(out + OFF_ACT + tid, v);
    }
}

extern "C" void kernel_launch(void* const* d_in, const int* in_sizes, int n_in,
                              void* d_out, int out_size, void* d_ws, size_t ws_size,
                              hipStream_t stream) {
    const float* x     = (const float*)d_in[0];
    const float* wg    = (const float*)d_in[1];
    const float* noise = (const float*)d_in[2];
    float* out = (float*)d_out;

    gemm_kernel<<<1024, 256, 0, stream>>>(x, wg, out);
    finish_kernel<<<T_TOKENS / 64, 1024, 0, stream>>>(noise, out);
}

// Round 8
// 255.222 us; speedup vs baseline: 1.6776x; 1.6776x over previous
//
#include <hip/hip_runtime.h>
#include <math.h>

// Problem constants (from reference setup_inputs)
#define T_TOKENS 16384
#define DIM      2048
#define NEXP     64
#define TOPK     2

#define NSUB  4              // k-subranges per block (wave groups)
#define KC    (DIM / NSUB)   // 512 k's per wave
#define PS    68             // partial-tile row stride (floats)
#define FS    68             // finish-kernel logit row stride

// Flat fp32 output layout: combine | topk_idx | gates | expert_activation
#define OFF_COMBINE 0
#define OFF_IDX     (T_TOKENS * NEXP)
#define OFF_GATES   (OFF_IDX + T_TOKENS * TOPK)
#define OFF_ACT     (OFF_GATES + T_TOKENS * TOPK)

__device__ __forceinline__ void fma16v(float* acc, float xs,
                                       const float4 w0, const float4 w1,
                                       const float4 w2, const float4 w3) {
    acc[0]  = fmaf(xs, w0.x, acc[0]);  acc[1]  = fmaf(xs, w0.y, acc[1]);
    acc[2]  = fmaf(xs, w0.z, acc[2]);  acc[3]  = fmaf(xs, w0.w, acc[3]);
    acc[4]  = fmaf(xs, w1.x, acc[4]);  acc[5]  = fmaf(xs, w1.y, acc[5]);
    acc[6]  = fmaf(xs, w1.z, acc[6]);  acc[7]  = fmaf(xs, w1.w, acc[7]);
    acc[8]  = fmaf(xs, w2.x, acc[8]);  acc[9]  = fmaf(xs, w2.y, acc[9]);
    acc[10] = fmaf(xs, w2.z, acc[10]); acc[11] = fmaf(xs, w2.w, acc[11]);
    acc[12] = fmaf(xs, w3.x, acc[12]); acc[13] = fmaf(xs, w3.y, acc[13]);
    acc[14] = fmaf(xs, w3.z, acc[14]); acc[15] = fmaf(xs, w3.w, acc[15]);
}

// Load 2 k-rows x 16 experts of w into 8 float4 registers.
#define LDW2(dst, base)                                                        \
    dst[0] = *reinterpret_cast<const float4*>((base) + 0);                     \
    dst[1] = *reinterpret_cast<const float4*>((base) + 4);                     \
    dst[2] = *reinterpret_cast<const float4*>((base) + 8);                     \
    dst[3] = *reinterpret_cast<const float4*>((base) + 12);                    \
    dst[4] = *reinterpret_cast<const float4*>((base) + NEXP + 0);              \
    dst[5] = *reinterpret_cast<const float4*>((base) + NEXP + 4);              \
    dst[6] = *reinterpret_cast<const float4*>((base) + NEXP + 8);              \
    dst[7] = *reinterpret_cast<const float4*>((base) + NEXP + 12);

// K1: GEMM. 256 blocks (one 64-row tile each; x read ONCE — no eg duplication),
// 1024 thr = 16 waves = 4 expert-groups x 4 k-subranges, lane = row, acc16.
//   - w: uniform-address VMEM loads (ds_bpermute taint blocks s_load promotion;
//     R6: that path alone took VALUBusy 28%->64%). Ping-pong wA/wB register
//     double-buffer forces a one-phase load-use distance in source dataflow so
//     LLVM cannot sink the loads (R7 failure mode: VGPR collapsed to 16).
//   - x: per-lane stream, X/Y/Z depth-2 rotation (R3's proven pattern).
// No LDS, no barriers in the K-loop. __launch_bounds__(1024,4) -> 128-reg cap.
__global__ __launch_bounds__(1024, 4)
void gemm_kernel(const float* __restrict__ x,
                 const float* __restrict__ w,     // [DIM][NEXP]
                 float* __restrict__ out) {       // logits -> combine region
    __shared__ float part[NSUB][64][PS];          // ~69.6 KB partial reduce

    const int tid  = threadIdx.x;
    const int lane = tid & 63;
    const int wv   = __builtin_amdgcn_readfirstlane(tid >> 6);
    const int eg   = wv & 3;              // experts [eg*16, eg*16+16)
    const int sub  = wv >> 2;             // k-subrange
    const int row  = blockIdx.x * 64 + lane;
    const int k0   = sub * KC;
    const int e0   = eg * 16;

    if (blockIdx.x == 0 && tid < NEXP) out[OFF_ACT + tid] = 0.0f;

    // Opaque per-lane zero: keeps w addresses in VGPRs so loads stay on VMEM.
    const int vz = __builtin_amdgcn_ds_bpermute(0, 0);

    float acc[16];
    #pragma unroll
    for (int i = 0; i < 16; ++i) acc[i] = 0.0f;

    const float* __restrict__ xp = x + (size_t)row * DIM + k0;
    const float* __restrict__ wq = w + vz + (size_t)k0 * NEXP + e0;

    float4 X = *reinterpret_cast<const float4*>(xp);
    float4 Y = *reinterpret_cast<const float4*>(xp + 4);

    float4 wA[8], wB[8];
    LDW2(wA, wq);                         // preload rows 0,1

    #pragma unroll 1
    for (int kk = 0; kk < KC; kk += 4) {
        // Load rows kk+2,kk+3 while FMAs consume rows kk,kk+1.
        LDW2(wB, wq + (size_t)(kk + 2) * NEXP);
        fma16v(acc, X.x, wA[0], wA[1], wA[2], wA[3]);
        fma16v(acc, X.y, wA[4], wA[5], wA[6], wA[7]);

        // Load next iteration's first half (uniform clamped index).
        const int kn = (kk + 4 < KC) ? (kk + 4) : 0;
        LDW2(wA, wq + (size_t)kn * NEXP);
        fma16v(acc, X.z, wB[0], wB[1], wB[2], wB[3]);
        fma16v(acc, X.w, wB[4], wB[5], wB[6], wB[7]);

        // x stream, 2 bodies ahead (clamped: harmless L1-hit at the tail).
        const int kpre = (kk + 8 < KC) ? (kk + 8) : 0;
        const float4 Z = *reinterpret_cast<const float4*>(xp + kpre);
        X = Y; Y = Z;
    }

    // Reduce the 4 k-subrange partials in LDS; coalesced float4 stores.
    {
        float* pr = &part[sub][lane][e0];
        *reinterpret_cast<float4*>(pr + 0)  = make_float4(acc[0],  acc[1],  acc[2],  acc[3]);
        *reinterpret_cast<float4*>(pr + 4)  = make_float4(acc[4],  acc[5],  acc[6],  acc[7]);
        *reinterpret_cast<float4*>(pr + 8)  = make_float4(acc[8],  acc[9],  acc[10], acc[11]);
        *reinterpret_cast<float4*>(pr + 12) = make_float4(acc[12], acc[13], acc[14], acc[15]);
    }
    __syncthreads();
    {
        const int r = tid >> 4, c = (tid & 15) * 4;
        float4 s        = *reinterpret_cast<const float4*>(&part[0][r][c]);
        const float4 s1 = *reinterpret_cast<const float4*>(&part[1][r][c]);
        const float4 s2 = *reinterpret_cast<const float4*>(&part[2][r][c]);
        const float4 s3 = *reinterpret_cast<const float4*>(&part[3][r][c]);
        s.x += s1.x + s2.x + s3.x;
        s.y += s1.y + s2.y + s3.y;
        s.z += s1.z + s2.z + s3.z;
        s.w += s1.w + s2.w + s3.w;
        *reinterpret_cast<float4*>(
            out + OFF_COMBINE + (size_t)(blockIdx.x * 64 + r) * NEXP + c) = s;
    }
}

// K2: logits (in combine region) + noise; top-2 + renormalized gates; writes
// all outputs, overwriting the logits with the combine tensor.
__global__ __launch_bounds__(1024)
void finish_kernel(const float* __restrict__ noise,
                   float* __restrict__ out) {
    __shared__ float lg[64][FS];
    __shared__ float g1s[64], g2s[64];
    __shared__ int   i1s[64], i2s[64];
    __shared__ float bins[NEXP];

    const int tid = threadIdx.x;
    const int r = tid >> 4, c = (tid & 15) * 4;
    const size_t rowbase = (size_t)(blockIdx.x * 64 + r) * NEXP + c;

    float4 a       = *reinterpret_cast<const float4*>(out + OFF_COMBINE + rowbase);
    const float4 n = *reinterpret_cast<const float4*>(noise + rowbase);
    a.x += n.x; a.y += n.y; a.z += n.z; a.w += n.w;
    *reinterpret_cast<float4*>(&lg[r][c]) = a;
    if (tid < NEXP) bins[tid] = 0.0f;
    __syncthreads();

    if (tid < 64) {   // wave 0, lane = row
        const int rr = tid;
        float m1 = -1e30f, m2 = -1e30f;
        int i1 = 0, i2 = 0;
        #pragma unroll
        for (int j = 0; j < NEXP; j += 4) {
            const float4 s = *reinterpret_cast<const float4*>(&lg[rr][j]);
            if (s.x > m1) { m2 = m1; i2 = i1; m1 = s.x; i1 = j + 0; } else if (s.x > m2) { m2 = s.x; i2 = j + 0; }
            if (s.y > m1) { m2 = m1; i2 = i1; m1 = s.y; i1 = j + 1; } else if (s.y > m2) { m2 = s.y; i2 = j + 1; }
            if (s.z > m1) { m2 = m1; i2 = i1; m1 = s.z; i1 = j + 2; } else if (s.z > m2) { m2 = s.z; i2 = j + 2; }
            if (s.w > m1) { m2 = m1; i2 = i1; m1 = s.w; i1 = j + 3; } else if (s.w > m2) { m2 = s.w; i2 = j + 3; }
        }
        // Softmax Z cancels under top-2 renorm: g1 = 1/(1+exp(l2-l1)).
        const float t  = expf(m2 - m1);
        const float g1 = 1.0f / (1.0f + t);
        const float g2 = 1.0f - g1;

        const int row = blockIdx.x * 64 + rr;
        out[OFF_IDX + row * 2 + 0]   = (float)i1;
        out[OFF_IDX + row * 2 + 1]   = (float)i2;
        out[OFF_GATES + row * 2 + 0] = g1;
        out[OFF_GATES + row * 2 + 1] = g2;

        g1s[rr] = g1; g2s[rr] = g2; i1s[rr] = i1; i2s[rr] = i2;
        atomicAdd(&bins[i1], 1.0f);
        atomicAdd(&bins[i2], 1.0f);
    }
    __syncthreads();

    {
        const int   ia = i1s[r], ib = i2s[r];
        const float ga = g1s[r], gb = g2s[r];
        float4 v;
        v.x = (c + 0 == ia) ? ga : (c + 0 == ib) ? gb : 0.0f;
        v.y = (c + 1 == ia) ? ga : (c + 1 == ib) ? gb : 0.0f;
        v.z = (c + 2 == ia) ? ga : (c + 2 == ib) ? gb : 0.0f;
        v.w = (c + 3 == ia) ? ga : (c + 3 == ib) ? gb : 0.0f;
        *reinterpret_cast<float4*>(out + OFF_COMBINE + rowbase) = v;
    }

    if (tid < NEXP) {
        const float v = bins[tid];
        if (v != 0.0f) atomicAdd(out + OFF_ACT + tid, v);
    }
}

extern "C" void kernel_launch(void* const* d_in, const int* in_sizes, int n_in,
                              void* d_out, int out_size, void* d_ws, size_t ws_size,
                              hipStream_t stream) {
    const float* x     = (const float*)d_in[0];
    const float* wg    = (const float*)d_in[1];
    const float* noise = (const float*)d_in[2];
    float* out = (float*)d_out;

    gemm_kernel<<<T_TOKENS / 64, 1024, 0, stream>>>(x, wg, out);
    finish_kernel<<<T_TOKENS / 64, 1024, 0, stream>>>(noise, out);
}